// Round 4
// baseline (798.769 us; speedup 1.0000x reference)
//
#include <hip/hip_runtime.h>

#define TPB 512   // 8 waves: wave w owns 16-col group w (H padded 100->128)

typedef __attribute__((ext_vector_type(8))) short bf16x8;
typedef __attribute__((ext_vector_type(4))) float f32x4;

// round-to-nearest-even fp32 -> bf16 (as raw short)
__device__ __forceinline__ short f2bf(float f) {
    union { float f; unsigned u; } v; v.f = f;
    unsigned r = (v.u + 0x7FFFu + ((v.u >> 16) & 1u)) >> 16;
    return (short)r;
}

__device__ __forceinline__ float frcp(float x) {
#if __has_builtin(__builtin_amdgcn_rcpf)
    return __builtin_amdgcn_rcpf(x);
#else
    return 1.0f / x;
#endif
}

__device__ __forceinline__ float fast_sig(float x) {
    return frcp(1.0f + __expf(-x));
}
__device__ __forceinline__ float fast_tanh(float x) {
    return 1.0f - 2.0f * frcp(1.0f + __expf(2.0f * x));
}

// lanes 0-31 keep a; lanes 32-63 receive b from (lane-32).
__device__ __forceinline__ float permlane_pack(float a, float b) {
#if __has_builtin(__builtin_amdgcn_permlane32_swap)
    // v_permlane32_swap_b32: new_vdst[32+i] = old_vsrc[i]; we use new_vdst only.
    auto r = __builtin_amdgcn_permlane32_swap(__float_as_int(a), __float_as_int(b),
                                              false, false);
    return __int_as_float(r[0]);
#else
    const int l  = (int)(threadIdx.x & 63);
    const int bs = __shfl(__float_as_int(b), l ^ 32, 64);
    return __int_as_float(l >= 32 ? bs : __float_as_int(a));
#endif
}

// Barrier that only drains LDS traffic. The x prefetch (global load, no LDS
// dest) and the out stores (no reader) may legally stay in flight across it —
// avoids the compiler's s_waitcnt vmcnt(0) drain (~900cy HBM latency exposed
// per step with __syncthreads()).
__device__ __forceinline__ void block_sync_lds() {
    asm volatile("s_waitcnt lgkmcnt(0)\n\ts_barrier" ::: "memory");
}

// ---------------------------------------------------------------------------
// Fully fused: z_t = x_t@Wi + h_{t-1}@Wh + bh -> gates (in registers) -> c,h
//              out_{t-1} = relu(h_{t-1} @ Wd + bd)  (reuses the aH fragments,
//              issued AFTER the h-write so it overlaps the barrier wait)
// grid 256 blocks x 8 batch rows, 512 threads (8 waves), 1 lgkm-barrier/step.
// Gate math redistributed over all 64 lanes via v_permlane32_swap_b32.
// Recurrence-critical Wh product uses TWO depth-2 dependent-MFMA chains
// (s{0,1} and s{2,3}) combined by one add; the off-critical Wi product stays
// a single depth-4 chain seeded with bh (its aX inputs are ready at barrier).
// Source order: aH reads -> aX reads -> Wh MFMAs -> Wi MFMAs, so the
// compiler's fine-grained lgkmcnt lets Wh start after only the aH returns.
// ---------------------------------------------------------------------------
__global__ __launch_bounds__(TPB, 2) void lstm_fused_all(
    const float* __restrict__ x,   // [2048,250,128]
    const float* __restrict__ Wi,  // [128,400]
    const float* __restrict__ Wh,  // [100,400]
    const float* __restrict__ bh,  // [400]
    const float* __restrict__ Wd,  // [100,100]
    const float* __restrict__ bd,  // [100]
    float* __restrict__ out)       // [2048,250,100]
{
    const int tid  = threadIdx.x;
    const int lane = tid & 63;
    const int wave = tid >> 6;    // 0..7, also the col group AND the staged x row
    const int m16  = lane & 15;
    const int kg   = lane >> 4;   // k-group 0..3 (MFMA fragment index)
    const int b0   = blockIdx.x * 8;

    __shared__ short xA[2][16 * 136];  // x_t bf16 A-layout [row][k], double buffered
    __shared__ short hA[2][16 * 136];  // h   bf16 A-layout, double buffered; pads stay 0

    for (int i = tid; i < 2 * 16 * 136; i += TPB) ((short*)xA)[i] = 0;
    for (int i = tid; i < 2 * 16 * 136; i += TPB) ((short*)hA)[i] = 0;

    const int  cg    = wave * 16 + m16;   // col within H-padded 128
    const bool valid = (cg < 100);

    // ---- preload fragments: Wi/Wh for all 4 gates of col group `wave`, Wd for out ----
    bf16x8 bWi[4][4], bWh[4][4], bWd[4];
    float  bhv[4];
    #pragma unroll
    for (int G = 0; G < 4; ++G) {
        const int c = G * 100 + cg;
        bhv[G] = valid ? bh[c] : 0.0f;
        #pragma unroll
        for (int s = 0; s < 4; ++s) {
            bf16x8 vi, vh;
            #pragma unroll
            for (int j = 0; j < 8; ++j) {
                const int k = s * 32 + kg * 8 + j;
                vi[j] = f2bf(valid ? Wi[k * 400 + c] : 0.0f);               // K=128 exact
                vh[j] = f2bf((valid && k < 100) ? Wh[k * 400 + c] : 0.0f);  // K pad 100->128
            }
            bWi[G][s] = vi;
            bWh[G][s] = vh;
        }
    }
    const float bdv = valid ? bd[cg] : 0.0f;
    #pragma unroll
    for (int s = 0; s < 4; ++s) {
        bf16x8 vd;
        #pragma unroll
        for (int j = 0; j < 8; ++j) {
            const int k = s * 32 + kg * 8 + j;
            vd[j] = f2bf((valid && k < 100) ? Wd[k * 100 + cg] : 0.0f);
        }
        bWd[s] = vd;
    }

    // redistributed row ownership: 2 rows per lane across ALL 64 lanes
    const int kgq     = (lane >> 4) & 1;                    // 0,1
    const int rowbase = kgq * 4 + ((lane >= 32) ? 2 : 0);   // rows {rowbase, rowbase+1}
    float myC[2] = {0.f, 0.f};
    long  ob2[2];
    #pragma unroll
    for (int j = 0; j < 2; ++j)
        ob2[j] = (long)(b0 + rowbase + j) * 25000 + cg;     // + t*100 at store time

    // x prefetch: wave w stages batch row w; lane covers 2 k's (float2, 512B/wave)
    const long xbase = ((long)(b0 + wave) * 250) * 128 + lane * 2;
    float2 xp = *(const float2*)&x[xbase];   // t = 0

    const int aoff = m16 * 136 + kg * 8;

    __syncthreads();   // LDS zeros visible before first staging writes

    #pragma unroll 1
    for (int t = 0; t <= 250; ++t) {
        const int buf = t & 1;
        if (t < 250) {
            // stage x_t (rows 0..7; rows 8..15 stay zero from init)
            short2 s2; s2.x = f2bf(xp.x); s2.y = f2bf(xp.y);
            *(short2*)&xA[buf][wave * 136 + lane * 2] = s2;
        }
        block_sync_lds();   // THE barrier: xA(t) + h(t-1) ds_writes visible; vmem stays in flight

        // prefetch x_{t+1} AFTER the barrier: full step in flight before its use
        if (t + 1 < 250)
            xp = *(const float2*)&x[xbase + (long)(t + 1) * 128];

        // h(t-1) fragments FIRST — on the recurrence critical path
        bf16x8 aH[4];
        #pragma unroll
        for (int s = 0; s < 4; ++s)
            aH[s] = *(const bf16x8*)&hA[buf][aoff + s * 32];

        // ---- z(t) = bh + x_t@Wi + h(t-1)@Wh ; gates in registers (CRITICAL PATH) ----
        if (t < 250) {
            // aX reads issued after aH so aH returns are waited on first
            bf16x8 aX[4];
            #pragma unroll
            for (int s = 0; s < 4; ++s)
                aX[s] = *(const bf16x8*)&xA[buf][aoff + s * 32];

            // critical Wh product: two independent depth-2 MFMA chains per gate
            f32x4 accH0[4], accH1[4];
            #pragma unroll
            for (int G = 0; G < 4; ++G) {
                const f32x4 zz = {0.f, 0.f, 0.f, 0.f};
                accH0[G] = __builtin_amdgcn_mfma_f32_16x16x32_bf16(aH[0], bWh[G][0], zz, 0, 0, 0);
                accH1[G] = __builtin_amdgcn_mfma_f32_16x16x32_bf16(aH[2], bWh[G][2], zz, 0, 0, 0);
            }
            #pragma unroll
            for (int G = 0; G < 4; ++G) {
                accH0[G] = __builtin_amdgcn_mfma_f32_16x16x32_bf16(aH[1], bWh[G][1], accH0[G], 0, 0, 0);
                accH1[G] = __builtin_amdgcn_mfma_f32_16x16x32_bf16(aH[3], bWh[G][3], accH1[G], 0, 0, 0);
            }

            // off-critical Wi product: depth-4 chain seeded with bh
            f32x4 accI[4];
            #pragma unroll
            for (int G = 0; G < 4; ++G) {
                const f32x4 a = {bhv[G], bhv[G], bhv[G], bhv[G]};
                accI[G] = a;
            }
            #pragma unroll
            for (int s = 0; s < 4; ++s) {
                #pragma unroll
                for (int G = 0; G < 4; ++G)
                    accI[G] = __builtin_amdgcn_mfma_f32_16x16x32_bf16(aX[s], bWi[G][s], accI[G], 0, 0, 0);
            }

            // z = accI + (accH0 + accH1); redistribute over all 64 lanes:
            // lane gets rows rowbase+{0,1}, col cg
            float z0[4], z1[4];
            #pragma unroll
            for (int G = 0; G < 4; ++G) {
                const f32x4 zs = accI[G] + (accH0[G] + accH1[G]);
                z0[G] = permlane_pack(zs[0], zs[2]);
                z1[G] = permlane_pack(zs[1], zs[3]);
            }
            if (valid) {
                {
                    const float ig = fast_sig(z0[0]);
                    const float fg = fast_sig(z0[1]);
                    const float gg = fast_tanh(z0[2]);
                    const float og = fast_sig(z0[3]);
                    const float cs = fg * myC[0] + ig * gg;
                    myC[0] = cs;
                    const float h = og * fast_tanh(cs);
                    hA[buf ^ 1][(rowbase + 0) * 136 + cg] = f2bf(h);
                }
                {
                    const float ig = fast_sig(z1[0]);
                    const float fg = fast_sig(z1[1]);
                    const float gg = fast_tanh(z1[2]);
                    const float og = fast_sig(z1[3]);
                    const float cs = fg * myC[1] + ig * gg;
                    myC[1] = cs;
                    const float h = og * fast_tanh(cs);
                    hA[buf ^ 1][(rowbase + 1) * 136 + cg] = f2bf(h);
                }
            }
        }

        // ---- out_{t-1} = relu(h(t-1) @ Wd + bd) — OFF the recurrence path;
        //      issued after the h-write so MFMA+stores overlap the barrier wait ----
        if (t > 0) {
            f32x4 oacc = {bdv, bdv, bdv, bdv};
            #pragma unroll
            for (int s = 0; s < 4; ++s)
                oacc = __builtin_amdgcn_mfma_f32_16x16x32_bf16(aH[s], bWd[s], oacc, 0, 0, 0);
            // redistribute: 2 outputs per lane over all 64 lanes
            const float o0 = permlane_pack(oacc[0], oacc[2]);
            const float o1 = permlane_pack(oacc[1], oacc[3]);
            if (valid) {
                out[ob2[0] + (long)(t - 1) * 100] = o0 > 0.0f ? o0 : 0.0f;
                out[ob2[1] + (long)(t - 1) * 100] = o1 > 0.0f ? o1 : 0.0f;
            }
        }
    }
}

extern "C" void kernel_launch(void* const* d_in, const int* in_sizes, int n_in,
                              void* d_out, int out_size, void* d_ws, size_t ws_size,
                              hipStream_t stream) {
    (void)in_sizes; (void)n_in; (void)out_size; (void)d_ws; (void)ws_size;
    const float* x  = (const float*)d_in[0];
    const float* Wi = (const float*)d_in[1];
    const float* Wh = (const float*)d_in[2];
    const float* bh = (const float*)d_in[3];
    const float* Wd = (const float*)d_in[4];
    const float* bd = (const float*)d_in[5];
    float* out = (float*)d_out;

    lstm_fused_all<<<256, TPB, 0, stream>>>(x, Wi, Wh, bh, Wd, bd, out);
}

// Round 6
// 679.671 us; speedup vs baseline: 1.1752x; 1.1752x over previous
//
#include <hip/hip_runtime.h>

#define TPB 448   // 7 waves: wave w owns 16-col group w (cols 0..111; H=100 real)

typedef __attribute__((ext_vector_type(8))) short bf16x8;
typedef __attribute__((ext_vector_type(4))) float f32x4;

// round-to-nearest-even fp32 -> bf16 (as raw short)
__device__ __forceinline__ short f2bf(float f) {
    union { float f; unsigned u; } v; v.f = f;
    unsigned r = (v.u + 0x7FFFu + ((v.u >> 16) & 1u)) >> 16;
    return (short)r;
}

__device__ __forceinline__ float frcp(float x) {
#if __has_builtin(__builtin_amdgcn_rcpf)
    return __builtin_amdgcn_rcpf(x);
#else
    return 1.0f / x;
#endif
}

__device__ __forceinline__ float fast_sig(float x) {
    return frcp(1.0f + __expf(-x));
}
__device__ __forceinline__ float fast_tanh(float x) {
    return 1.0f - 2.0f * frcp(1.0f + __expf(2.0f * x));
}

// lanes 0-31 keep a; lanes 32-63 receive b[lane-32].
__device__ __forceinline__ float permlane_pack(float a, float b) {
#if __has_builtin(__builtin_amdgcn_permlane32_swap)
    auto r = __builtin_amdgcn_permlane32_swap(__float_as_int(a), __float_as_int(b),
                                              false, false);
    return __int_as_float(r[0]);
#else
    const int l  = (int)(threadIdx.x & 63);
    const int bs = __shfl(__float_as_int(b), l ^ 32, 64);
    return __int_as_float(l >= 32 ? bs : __float_as_int(a));
#endif
}

// Barrier that only drains LDS traffic: x prefetch loads and out stores stay
// in flight across it (no vmcnt(0) drain -> no exposed HBM latency per step).
__device__ __forceinline__ void block_sync_lds() {
    asm volatile("s_waitcnt lgkmcnt(0)\n\ts_barrier" ::: "memory");
}

// ---------------------------------------------------------------------------
// Fused LSTM, software-pipelined one step ahead on the x@Wi product:
//   critical segment per step: barrier -> ds_read aH -> 16 Wh-MFMA (2 depth-2
//   chains) -> z = accI + zH -> permlane -> gates -> h ds_write
//   shadow (overlaps barrier wait): accI(t+1) = bh + x(t+1)@Wi  (16 MFMA),
//   out_{t-1} = relu(h(t-1)@Wd + bd), x staging + prefetch.
// xA is TRIPLE-buffered: the step-t writer targets (t+1)%3 while the slowest
// reader (step t, post-barrier) holds (t)%3 and the t-1 buffer is already
// drained — each wave's lgkmcnt(0) at barrier arrival retires its ds_reads,
// and no wave can be a full barrier generation ahead of another.
// 7 waves (448 thr): wave 7 of the 8-wave layout was 100% padding work;
// wave 0 stages x row 7 in addition to row 0 (second prefetch stream).
// ---------------------------------------------------------------------------
__global__ __launch_bounds__(TPB, 2) void lstm_fused_all(
    const float* __restrict__ x,   // [2048,250,128]
    const float* __restrict__ Wi,  // [128,400]
    const float* __restrict__ Wh,  // [100,400]
    const float* __restrict__ bh,  // [400]
    const float* __restrict__ Wd,  // [100,100]
    const float* __restrict__ bd,  // [100]
    float* __restrict__ out)       // [2048,250,100]
{
    const int tid  = threadIdx.x;
    const int lane = tid & 63;
    const int wave = tid >> 6;    // 0..6, also the col group
    const int m16  = lane & 15;
    const int kg   = lane >> 4;   // k-group 0..3 (MFMA fragment index)
    const int b0   = blockIdx.x * 8;

    __shared__ short xA[3][16 * 136];  // x bf16 A-layout, TRIPLE buffered
    __shared__ short hA[2][16 * 136];  // h bf16 A-layout, double buffered

    for (int i = tid; i < 3 * 16 * 136; i += TPB) ((short*)xA)[i] = 0;
    for (int i = tid; i < 2 * 16 * 136; i += TPB) ((short*)hA)[i] = 0;

    const int  cg    = wave * 16 + m16;   // col within H-padded 112
    const bool valid = (cg < 100);

    // ---- preload fragments: Wi/Wh for all 4 gates of col group `wave`, Wd ----
    bf16x8 bWi[4][4], bWh[4][4], bWd[4];
    float  bhv[4];
    #pragma unroll
    for (int G = 0; G < 4; ++G) {
        const int c = G * 100 + cg;
        bhv[G] = valid ? bh[c] : 0.0f;
        #pragma unroll
        for (int s = 0; s < 4; ++s) {
            bf16x8 vi, vh;
            #pragma unroll
            for (int j = 0; j < 8; ++j) {
                const int k = s * 32 + kg * 8 + j;
                vi[j] = f2bf(valid ? Wi[k * 400 + c] : 0.0f);               // K=128 exact
                vh[j] = f2bf((valid && k < 100) ? Wh[k * 400 + c] : 0.0f);  // K pad
            }
            bWi[G][s] = vi;
            bWh[G][s] = vh;
        }
    }
    const float bdv = valid ? bd[cg] : 0.0f;
    #pragma unroll
    for (int s = 0; s < 4; ++s) {
        bf16x8 vd;
        #pragma unroll
        for (int j = 0; j < 8; ++j) {
            const int k = s * 32 + kg * 8 + j;
            vd[j] = f2bf((valid && k < 100) ? Wd[k * 100 + cg] : 0.0f);
        }
        bWd[s] = vd;
    }

    // row ownership for gates/out: 2 rows per lane over all 64 lanes
    const int kgq     = (lane >> 4) & 1;                    // 0,1
    const int rowbase = kgq * 4 + ((lane >= 32) ? 2 : 0);   // rows {rowbase, rowbase+1}
    float myC[2] = {0.f, 0.f};
    long  ob2[2];
    #pragma unroll
    for (int j = 0; j < 2; ++j)
        ob2[j] = (long)(b0 + rowbase + j) * 25000 + cg;     // + (t-1)*100 at store

    // x prefetch, depth 2: la = x(t+1) at loop top, lb = x(t+2).
    // wave w stages row w; wave 0 ALSO stages row 7 (second stream).
    const long xb0 = ((long)(b0 + wave) * 250) * 128 + lane * 2;
    const long xb1 = ((long)(b0 + 7)    * 250) * 128 + lane * 2;  // wave 0 only
    float2 la0, la1 = {0.f, 0.f}, lb0, lb1 = {0.f, 0.f};
    la0 = *(const float2*)&x[xb0];                    // x(0), row wave
    if (wave == 0) la1 = *(const float2*)&x[xb1];     // x(0), row 7
    lb0 = *(const float2*)&x[xb0 + 128];              // x(1)
    if (wave == 0) lb1 = *(const float2*)&x[xb1 + 128];

    const int aoff = m16 * 136 + kg * 8;

    __syncthreads();   // LDS zeros visible

    // ---- prologue: stage x(0) into xA[0]; accI(0) = bh + x(0)@Wi ----
    {
        short2 s0; s0.x = f2bf(la0.x); s0.y = f2bf(la0.y);
        *(short2*)&xA[0][wave * 136 + lane * 2] = s0;
        if (wave == 0) {
            short2 s1; s1.x = f2bf(la1.x); s1.y = f2bf(la1.y);
            *(short2*)&xA[0][7 * 136 + lane * 2] = s1;
        }
    }
    __syncthreads();   // x(0) visible
    la0 = lb0; if (wave == 0) la1 = lb1;              // la = x(1)
    lb0 = *(const float2*)&x[xb0 + 2 * 128];          // lb = x(2)
    if (wave == 0) lb1 = *(const float2*)&x[xb1 + 2 * 128];

    f32x4 accI[4];
    {
        bf16x8 aX[4];
        #pragma unroll
        for (int s = 0; s < 4; ++s)
            aX[s] = *(const bf16x8*)&xA[0][aoff + s * 32];
        #pragma unroll
        for (int G = 0; G < 4; ++G) {
            const f32x4 a = {bhv[G], bhv[G], bhv[G], bhv[G]};
            accI[G] = a;
        }
        #pragma unroll
        for (int s = 0; s < 4; ++s)
            #pragma unroll
            for (int G = 0; G < 4; ++G)
                accI[G] = __builtin_amdgcn_mfma_f32_16x16x32_bf16(aX[s], bWi[G][s], accI[G], 0, 0, 0);
    }

    int  bufx = 1;        // (t+1)%3 rotation
    int  ooff = 0;        // (t-1)*100 at out-store time
    long xoff = 3 * 128;  // (t+3)*128 for the lb load

    #pragma unroll 1
    for (int t = 0; t <= 250; ++t) {
        const int bufh = t & 1;

        // stage x(t+1) pre-barrier (triple buffer: race-free vs t-1 readers)
        if (t + 1 < 250) {
            short2 s0; s0.x = f2bf(la0.x); s0.y = f2bf(la0.y);
            *(short2*)&xA[bufx][wave * 136 + lane * 2] = s0;
            if (wave == 0) {
                short2 s1; s1.x = f2bf(la1.x); s1.y = f2bf(la1.y);
                *(short2*)&xA[bufx][7 * 136 + lane * 2] = s1;
            }
        }
        block_sync_lds();  // x(t+1) + h(t-1) ds_writes visible; vmem in flight

        // rotate prefetch; issue next load after the barrier
        if (t + 1 < 250) { la0 = lb0; if (wave == 0) la1 = lb1; }
        if (t + 3 < 250) {
            lb0 = *(const float2*)&x[xb0 + xoff];
            if (wave == 0) lb1 = *(const float2*)&x[xb1 + xoff];
        }
        xoff += 128;

        // h(t-1) fragments — z-GEMM (critical) and out-GEMM (shadow)
        bf16x8 aH[4];
        #pragma unroll
        for (int s = 0; s < 4; ++s)
            aH[s] = *(const bf16x8*)&hA[bufh][aoff + s * 32];

        // ---- CRITICAL: z(t) = accI(t) + h(t-1)@Wh -> gates -> c,h ----
        if (t < 250) {
            f32x4 accH0[4], accH1[4];
            #pragma unroll
            for (int G = 0; G < 4; ++G) {
                const f32x4 zz = {0.f, 0.f, 0.f, 0.f};
                accH0[G] = __builtin_amdgcn_mfma_f32_16x16x32_bf16(aH[0], bWh[G][0], zz, 0, 0, 0);
                accH1[G] = __builtin_amdgcn_mfma_f32_16x16x32_bf16(aH[2], bWh[G][2], zz, 0, 0, 0);
            }
            #pragma unroll
            for (int G = 0; G < 4; ++G) {
                accH0[G] = __builtin_amdgcn_mfma_f32_16x16x32_bf16(aH[1], bWh[G][1], accH0[G], 0, 0, 0);
                accH1[G] = __builtin_amdgcn_mfma_f32_16x16x32_bf16(aH[3], bWh[G][3], accH1[G], 0, 0, 0);
            }

            float z0[4], z1[4];
            #pragma unroll
            for (int G = 0; G < 4; ++G) {
                const f32x4 zs = accI[G] + (accH0[G] + accH1[G]);
                z0[G] = permlane_pack(zs[0], zs[2]);
                z1[G] = permlane_pack(zs[1], zs[3]);
            }
            if (valid) {
                {
                    const float ig = fast_sig(z0[0]);
                    const float fg = fast_sig(z0[1]);
                    const float gg = fast_tanh(z0[2]);
                    const float og = fast_sig(z0[3]);
                    const float cs = fg * myC[0] + ig * gg;
                    myC[0] = cs;
                    const float h = og * fast_tanh(cs);
                    hA[bufh ^ 1][(rowbase + 0) * 136 + cg] = f2bf(h);
                }
                {
                    const float ig = fast_sig(z1[0]);
                    const float fg = fast_sig(z1[1]);
                    const float gg = fast_tanh(z1[2]);
                    const float og = fast_sig(z1[3]);
                    const float cs = fg * myC[1] + ig * gg;
                    myC[1] = cs;
                    const float h = og * fast_tanh(cs);
                    hA[bufh ^ 1][(rowbase + 1) * 136 + cg] = f2bf(h);
                }
            }
        }

        // ---- SHADOW 1: accI(t+1) = bh + x(t+1)@Wi (overlaps barrier wait) ----
        if (t + 1 < 250) {
            bf16x8 aX[4];
            #pragma unroll
            for (int s = 0; s < 4; ++s)
                aX[s] = *(const bf16x8*)&xA[bufx][aoff + s * 32];
            #pragma unroll
            for (int G = 0; G < 4; ++G) {
                const f32x4 a = {bhv[G], bhv[G], bhv[G], bhv[G]};
                accI[G] = a;
            }
            #pragma unroll
            for (int s = 0; s < 4; ++s)
                #pragma unroll
                for (int G = 0; G < 4; ++G)
                    accI[G] = __builtin_amdgcn_mfma_f32_16x16x32_bf16(aX[s], bWi[G][s], accI[G], 0, 0, 0);
            bufx = (bufx == 2) ? 0 : bufx + 1;
        }

        // ---- SHADOW 2: out_{t-1} = relu(h(t-1)@Wd + bd) ----
        if (t > 0) {
            f32x4 oacc = {bdv, bdv, bdv, bdv};
            #pragma unroll
            for (int s = 0; s < 4; ++s)
                oacc = __builtin_amdgcn_mfma_f32_16x16x32_bf16(aH[s], bWd[s], oacc, 0, 0, 0);
            const float o0 = permlane_pack(oacc[0], oacc[2]);
            const float o1 = permlane_pack(oacc[1], oacc[3]);
            if (valid) {
                out[ob2[0] + ooff] = o0 > 0.0f ? o0 : 0.0f;
                out[ob2[1] + ooff] = o1 > 0.0f ? o1 : 0.0f;
            }
            ooff += 100;
        }
    }
}

extern "C" void kernel_launch(void* const* d_in, const int* in_sizes, int n_in,
                              void* d_out, int out_size, void* d_ws, size_t ws_size,
                              hipStream_t stream) {
    (void)in_sizes; (void)n_in; (void)out_size; (void)d_ws; (void)ws_size;
    const float* x  = (const float*)d_in[0];
    const float* Wi = (const float*)d_in[1];
    const float* Wh = (const float*)d_in[2];
    const float* bh = (const float*)d_in[3];
    const float* Wd = (const float*)d_in[4];
    const float* bd = (const float*)d_in[5];
    float* out = (float*)d_out;

    lstm_fused_all<<<256, TPB, 0, stream>>>(x, Wi, Wh, bh, Wd, bd, out);
}